// Round 1
// baseline (641.386 us; speedup 1.0000x reference)
//
#include <hip/hip_runtime.h>
#include <hip/hip_bf16.h>
#include <math.h>

#define Bb 2
#define Lq 384
#define Sk 384
#define Dd 512
#define Hh 256

// workspace layout (bytes)
#define HQ_OFF   0                          // B*L*H floats  = 786432 B
#define HK_OFF   (HQ_OFF + Bb*Lq*Hh*4)      // B*S*H floats  = 786432 B
#define SIM_OFF  (HK_OFF + Bb*Sk*Hh*4)      // B*L*S floats  = 1179648 B
#define SCAL_OFF (SIM_OFF + Bb*Lq*Sk*4)     // 2 floats
#define CNT_OFF  (SCAL_OFF + 16)            // 1 int
#define LIST_OFF (CNT_OFF + 16)             // LIST_CAP ints
#define LIST_CAP (Bb*Lq*Sk)

#define PROJ_ROWS 8

// ---------------------------------------------------------------------------
// prep: GWsum = sum(gamma*W2), bconst = sum(beta*W2) + b2
__global__ __launch_bounds__(256) void prep_kernel(
    const float* __restrict__ gam, const float* __restrict__ bet,
    const float* __restrict__ W2, const float* __restrict__ b2,
    float* __restrict__ scal)
{
    __shared__ float s1[256], s2[256];
    int t = threadIdx.x;
    s1[t] = gam[t] * W2[t];
    s2[t] = bet[t] * W2[t];
    __syncthreads();
    for (int o = 128; o > 0; o >>= 1) {
        if (t < o) { s1[t] += s1[t + o]; s2[t] += s2[t + o]; }
        __syncthreads();
    }
    if (t == 0) { scal[0] = s1[0]; scal[1] = s2[0] + b2[0]; }
}

// ---------------------------------------------------------------------------
// projection: hq[b,l,h] = q[b,l,:]@Wq + qg[b,:]@Wqg + b1[h]
//             hk[b,s,h] = k[b,s,:]@Wk + kg[b,:]@Wkg
__global__ __launch_bounds__(256) void proj_kernel(
    const float* __restrict__ q, const float* __restrict__ k,
    const float* __restrict__ qg, const float* __restrict__ kg,
    const float* __restrict__ W1, const float* __restrict__ b1,
    float* __restrict__ hq, float* __restrict__ hk)
{
    __shared__ float tile[PROJ_ROWS * Dd];
    int tid = threadIdx.x;
    const int tpb  = Lq / PROJ_ROWS;     // 48
    const int half = Bb * tpb;           // 96
    int bx = blockIdx.x;
    bool isQ = bx < half;
    int bb = isQ ? bx : bx - half;
    int b  = bb / tpb;
    int rt = bb % tpb;
    const float* src  = isQ ? q  : k;
    const float* glob = isQ ? qg : kg;
    int woff_m = isQ ? 0           : Dd * Hh;
    int woff_g = isQ ? 2 * Dd * Hh : 3 * Dd * Hh;
    float* dst = isQ ? hq : hk;

    int base = (b * Lq + rt * PROJ_ROWS) * Dd;
    for (int i = tid; i < PROJ_ROWS * Dd; i += 256) tile[i] = src[base + i];
    __syncthreads();

    float acc[PROJ_ROWS];
#pragma unroll
    for (int r = 0; r < PROJ_ROWS; ++r) acc[r] = 0.f;
    for (int d = 0; d < Dd; ++d) {
        float w = W1[woff_m + d * Hh + tid];
#pragma unroll
        for (int r = 0; r < PROJ_ROWS; ++r)
            acc[r] = fmaf(tile[r * Dd + d], w, acc[r]);
    }
    float gacc = 0.f;
    const float* gb = glob + b * Dd;
    for (int d = 0; d < Dd; ++d)
        gacc = fmaf(gb[d], W1[woff_g + d * Hh + tid], gacc);
    float bias = gacc + (isQ ? b1[tid] : 0.f);
    int obase = (b * Lq + rt * PROJ_ROWS) * Hh + tid;
#pragma unroll
    for (int r = 0; r < PROJ_ROWS; ++r)
        dst[obase + r * Hh] = acc[r] + bias;
}

// ---------------------------------------------------------------------------
// sim[b,l,s] = q[b,l,:]·k[b,s,:] / sqrt(D)
__global__ __launch_bounds__(256) void sim_kernel(
    const float* __restrict__ q, const float* __restrict__ k,
    float* __restrict__ sim)
{
    __shared__ float qs[16][129];
    __shared__ float ks[16][129];
    int tid = threadIdx.x;
    int bx = blockIdx.x;
    int b  = bx / (24 * 24);
    int r  = bx % (24 * 24);
    int lt = r / 24, st = r % 24;
    int tl = tid >> 4, ts = tid & 15;
    const float* qb = q + (b * Lq + lt * 16) * Dd;
    const float* kb = k + (b * Sk + st * 16) * Dd;
    float acc = 0.f;
    for (int c = 0; c < Dd; c += 128) {
        __syncthreads();
#pragma unroll
        for (int i = 0; i < 8; ++i) {
            int li = i * 256 + tid;        // 0..2047
            int row = li >> 7, col = li & 127;
            qs[row][col] = qb[row * Dd + c + col];
            ks[row][col] = kb[row * Dd + c + col];
        }
        __syncthreads();
#pragma unroll 8
        for (int dd = 0; dd < 128; ++dd)
            acc = fmaf(qs[tl][dd], ks[ts][dd], acc);
    }
    int l = lt * 16 + tl, s = st * 16 + ts;
    sim[(b * Lq + l) * Sk + s] = acc * 0.04419417382415922f; // 1/sqrt(512)
}

// ---------------------------------------------------------------------------
// main: per (b,l,s): one pass over H accumulating s1,s2,sw -> threshold ->
// gumbel decision; flag borderline |t|<1e-3 for f64 cleanup.
__global__ __launch_bounds__(256) void main_kernel(
    const float* __restrict__ hq, const float* __restrict__ hk,
    const float* __restrict__ sim, const float* __restrict__ gam,
    const float* __restrict__ W2, const float* __restrict__ scal,
    const float* __restrict__ gu, float* __restrict__ out,
    int* __restrict__ cnt, int* __restrict__ list)
{
    __shared__ float hq_t[16][257];
    __shared__ float hk_t[16][257];
    __shared__ float gw_s[256];
    int tid = threadIdx.x;
    int bx = blockIdx.x;
    int b  = bx / (24 * 24);
    int r  = bx % (24 * 24);
    int lt = r / 24, st = r % 24;

    const float* hqb = hq + (b * Lq + lt * 16) * Hh;
    const float* hkb = hk + (b * Sk + st * 16) * Hh;
#pragma unroll
    for (int kk = 0; kk < 16; ++kk) {
        hq_t[kk][tid] = hqb[kk * Hh + tid];
        hk_t[kk][tid] = hkb[kk * Hh + tid];
    }
    gw_s[tid] = gam[tid] * W2[tid];
    __syncthreads();

    int tl = tid >> 4, ts = tid & 15;
    float s1 = 0.f, s2 = 0.f, sw = 0.f;
    for (int h = 0; h < Hh; ++h) {
        float x = hq_t[tl][h] + hk_t[ts][h];
        float y = 0.5f * x * (1.0f + erff(x * 0.70710678118654752f));
        s1 += y;
        s2 = fmaf(y, y, s2);
        sw = fmaf(y, gw_s[h], sw);
    }
    float mu   = s1 * (1.0f / 256.0f);
    float var  = s2 * (1.0f / 256.0f) - mu * mu;
    float rstd = rsqrtf(var + 1e-5f);
    float thr  = rstd * (sw - mu * scal[0]) + scal[1];

    int l = lt * 16 + tl, s = st * 16 + ts;
    int idx = (b * Lq + l) * Sk + s;
    float  sv = sim[idx];
    float2 uv = reinterpret_cast<const float2*>(gu)[idx];
    float u0 = fminf(fmaxf(uv.x, 1e-6f), 1.0f - 1e-6f);
    float u1 = fminf(fmaxf(uv.y, 1e-6f), 1.0f - 1e-6f);
    float g0 = -logf(-logf(u0));
    float g1 = -logf(-logf(u1));
    float t  = 0.2f * (sv - thr) + (g1 - g0);
    out[idx] = t > 0.0f ? 1.0f : 0.0f;
    if (fabsf(t) < 1e-3f) {
        int p = atomicAdd(cnt, 1);
        if (p < LIST_CAP) list[p] = idx;
    }
}

// ---------------------------------------------------------------------------
__device__ __forceinline__ double block_sum(double* sd, double v, int tid)
{
    __syncthreads();
    sd[tid] = v;
    __syncthreads();
    for (int o = 128; o > 0; o >>= 1) {
        if (tid < o) sd[tid] += sd[tid + o];
        __syncthreads();
    }
    return sd[0];
}

// f64 recompute of flagged borderline samples (matches np float64 reference)
__global__ __launch_bounds__(256) void cleanup_kernel(
    const float* __restrict__ q, const float* __restrict__ k,
    const float* __restrict__ qg, const float* __restrict__ kg,
    const float* __restrict__ W1, const float* __restrict__ b1,
    const float* __restrict__ gam, const float* __restrict__ bet,
    const float* __restrict__ W2, const float* __restrict__ b2,
    const float* __restrict__ gu, float* __restrict__ out,
    const int* __restrict__ cnt, const int* __restrict__ list)
{
    __shared__ double sd[256];
    int tid = threadIdx.x;
    int n = *cnt;
    if (n > LIST_CAP) n = LIST_CAP;
    for (int it = blockIdx.x; it < n; it += gridDim.x) {
        int idx = list[it];
        int b   = idx / (Lq * Sk);
        int rem = idx % (Lq * Sk);
        int l = rem / Sk, s = rem % Sk;
        const float* qrow = q + (b * Lq + l) * Dd;
        const float* krow = k + (b * Sk + s) * Dd;
        const float* qgb  = qg + b * Dd;
        const float* kgb  = kg + b * Dd;
        int h = tid;
        double a1 = 0, a2 = 0, a3 = 0, a4 = 0;
        for (int d = 0; d < Dd; ++d) {
            a1 += (double)qrow[d] * (double)W1[d * Hh + h];
            a2 += (double)qgb[d]  * (double)W1[(2 * Dd + d) * Hh + h];
            a3 += (double)krow[d] * (double)W1[(Dd + d) * Hh + h];
            a4 += (double)kgb[d]  * (double)W1[(3 * Dd + d) * Hh + h];
        }
        double x = (a1 + a2) + (a3 + a4) + (double)b1[h];
        double y = 0.5 * x * (1.0 + erf(x * 0.70710678118654752440));
        double mu   = block_sum(sd, y, tid) / 256.0;
        double dev  = y - mu;
        double var  = block_sum(sd, dev * dev, tid) / 256.0;
        double rstd = 1.0 / sqrt(var + 1e-5);
        double nrm  = dev * rstd * (double)gam[h] + (double)bet[h];
        double thr  = block_sum(sd, nrm * (double)W2[h], tid) + (double)b2[0];
        double sp   = (double)qrow[h] * (double)krow[h]
                    + (double)qrow[h + 256] * (double)krow[h + 256];
        double simv = block_sum(sd, sp, tid) / 22.627416997969522; // sqrt(512)
        if (tid == 0) {
            float2 uv = reinterpret_cast<const float2*>(gu)[idx];
            double u0 = fmin(fmax((double)uv.x, 1e-6), 1.0 - 1e-6);
            double u1 = fmin(fmax((double)uv.y, 1e-6), 1.0 - 1e-6);
            double g0 = -log(-log(u0));
            double g1 = -log(-log(u1));
            double lg = (simv - thr) / 10.0;
            double t  = 2.0 * lg + (g1 - g0);
            out[idx] = t > 0.0 ? 1.0f : 0.0f;
        }
        __syncthreads();
    }
}

// ---------------------------------------------------------------------------
extern "C" void kernel_launch(void* const* d_in, const int* in_sizes, int n_in,
                              void* d_out, int out_size, void* d_ws, size_t ws_size,
                              hipStream_t stream)
{
    const float* q   = (const float*)d_in[0];
    const float* k   = (const float*)d_in[1];
    const float* qg  = (const float*)d_in[2];
    const float* kg  = (const float*)d_in[3];
    const float* W1  = (const float*)d_in[4];
    const float* b1  = (const float*)d_in[5];
    const float* gam = (const float*)d_in[6];
    const float* bet = (const float*)d_in[7];
    const float* W2  = (const float*)d_in[8];
    const float* b2  = (const float*)d_in[9];
    const float* gu  = (const float*)d_in[10];
    float* out = (float*)d_out;

    char*  ws   = (char*)d_ws;
    float* hq   = (float*)(ws + HQ_OFF);
    float* hk   = (float*)(ws + HK_OFF);
    float* sim  = (float*)(ws + SIM_OFF);
    float* scal = (float*)(ws + SCAL_OFF);
    int*   cnt  = (int*)(ws + CNT_OFF);
    int*   list = (int*)(ws + LIST_OFF);

    hipMemsetAsync(cnt, 0, sizeof(int), stream);
    prep_kernel<<<1, 256, 0, stream>>>(gam, bet, W2, b2, scal);
    proj_kernel<<<2 * Bb * (Lq / PROJ_ROWS), 256, 0, stream>>>(
        q, k, qg, kg, W1, b1, hq, hk);
    sim_kernel<<<Bb * 24 * 24, 256, 0, stream>>>(q, k, sim);
    main_kernel<<<Bb * 24 * 24, 256, 0, stream>>>(
        hq, hk, sim, gam, W2, scal, gu, out, cnt, list);
    cleanup_kernel<<<256, 256, 0, stream>>>(
        q, k, qg, kg, W1, b1, gam, bet, W2, b2, gu, out, cnt, list);
}

// Round 2
// 254.551 us; speedup vs baseline: 2.5197x; 2.5197x over previous
//
#include <hip/hip_runtime.h>
#include <hip/hip_bf16.h>
#include <math.h>

#define Bb 2
#define Lq 384
#define Sk 384
#define Dd 512
#define Hh 256

#define PROJ_ROWS 8
#define LIST_CAP 65536

// workspace layout (bytes) — f64 regions first for 8B alignment
#define HQD_OFF  0                                   // B*L*H doubles = 1572864
#define HKD_OFF  (HQD_OFF + Bb*Lq*Hh*8)              // B*S*H doubles = 1572864
#define GQD_OFF  (HKD_OFF + Bb*Sk*Hh*8)              // B*H doubles (+pad)
#define GKD_OFF  (GQD_OFF + 4096)
#define HQ_OFF   (GKD_OFF + 4096)                    // B*L*H floats = 786432
#define HK_OFF   (HQ_OFF + Bb*Lq*Hh*4)               // B*S*H floats
#define SIM_OFF  (HK_OFF + Bb*Sk*Hh*4)               // B*L*S floats = 1179648
#define SCAL_OFF (SIM_OFF + Bb*Lq*Sk*4)              // 2 floats
#define CNT_OFF  (SCAL_OFF + 16)                     // 1 int
#define LIST_OFF (CNT_OFF + 16)                      // LIST_CAP ints

// ---------------------------------------------------------------------------
// prep: scal[0] = sum(gamma*W2), scal[1] = sum(beta*W2) + b2   (f32, for main)
__global__ __launch_bounds__(256) void prep_kernel(
    const float* __restrict__ gam, const float* __restrict__ bet,
    const float* __restrict__ W2, const float* __restrict__ b2,
    float* __restrict__ scal)
{
    __shared__ float s1[256], s2[256];
    int t = threadIdx.x;
    s1[t] = gam[t] * W2[t];
    s2[t] = bet[t] * W2[t];
    __syncthreads();
    for (int o = 128; o > 0; o >>= 1) {
        if (t < o) { s1[t] += s1[t + o]; s2[t] += s2[t + o]; }
        __syncthreads();
    }
    if (t == 0) { scal[0] = s1[0]; scal[1] = s2[0] + b2[0]; }
}

// ---------------------------------------------------------------------------
// globald: gq_d[b,h] = qg[b,:]@Wqg + b1[h]  (f64);  gk_d[b,h] = kg[b,:]@Wkg
__global__ __launch_bounds__(256) void globald_kernel(
    const float* __restrict__ qg, const float* __restrict__ kg,
    const float* __restrict__ W1, const float* __restrict__ b1,
    double* __restrict__ gq_d, double* __restrict__ gk_d)
{
    int tid = threadIdx.x;
    int bx = blockIdx.x;                 // 0..2*Bb-1
    bool isQ = bx < Bb;
    int b = isQ ? bx : bx - Bb;
    const float* gv = (isQ ? qg : kg) + b * Dd;
    int woff = isQ ? 2 * Dd * Hh : 3 * Dd * Hh;
    double a0 = 0, a1 = 0, a2 = 0, a3 = 0;
    for (int d = 0; d < Dd; d += 4) {
        a0 = fma((double)gv[d + 0], (double)W1[woff + (d + 0) * Hh + tid], a0);
        a1 = fma((double)gv[d + 1], (double)W1[woff + (d + 1) * Hh + tid], a1);
        a2 = fma((double)gv[d + 2], (double)W1[woff + (d + 2) * Hh + tid], a2);
        a3 = fma((double)gv[d + 3], (double)W1[woff + (d + 3) * Hh + tid], a3);
    }
    double s = ((a0 + a1) + (a2 + a3)) + (isQ ? (double)b1[tid] : 0.0);
    (isQ ? gq_d : gk_d)[b * Hh + tid] = s;
}

// ---------------------------------------------------------------------------
// projd: f64 row projections for ALL rows; also emits f32 hq/hk (with
// global+bias folded) for the fast path.
__global__ __launch_bounds__(256) void projd_kernel(
    const float* __restrict__ q, const float* __restrict__ k,
    const float* __restrict__ W1,
    const double* __restrict__ gq_d, const double* __restrict__ gk_d,
    double* __restrict__ hq_d, double* __restrict__ hk_d,
    float* __restrict__ hq, float* __restrict__ hk)
{
    __shared__ double tile[PROJ_ROWS * Dd];   // 32 KB
    int tid = threadIdx.x;
    const int tpb  = Lq / PROJ_ROWS;     // 48
    const int half = Bb * tpb;           // 96
    int bx = blockIdx.x;
    bool isQ = bx < half;
    int bb = isQ ? bx : bx - half;
    int b  = bb / tpb;
    int rt = bb % tpb;
    const float*  src = isQ ? q : k;
    const double* gl  = isQ ? gq_d : gk_d;
    int woff = isQ ? 0 : Dd * Hh;
    double* dstd = isQ ? hq_d : hk_d;
    float*  dstf = isQ ? hq : hk;

    int base = (b * Lq + rt * PROJ_ROWS) * Dd;
    for (int i = tid; i < PROJ_ROWS * Dd; i += 256)
        tile[i] = (double)src[base + i];
    __syncthreads();

    double acc[PROJ_ROWS];
#pragma unroll
    for (int r = 0; r < PROJ_ROWS; ++r) acc[r] = 0.0;
    for (int d = 0; d < Dd; ++d) {
        double w = (double)W1[woff + d * Hh + tid];
#pragma unroll
        for (int r = 0; r < PROJ_ROWS; ++r)
            acc[r] = fma(tile[r * Dd + d], w, acc[r]);
    }
    double g = gl[b * Hh + tid];
    int ob = (b * Lq + rt * PROJ_ROWS) * Hh + tid;
#pragma unroll
    for (int r = 0; r < PROJ_ROWS; ++r) {
        dstd[ob + r * Hh] = acc[r];
        dstf[ob + r * Hh] = (float)(acc[r] + g);
    }
}

// ---------------------------------------------------------------------------
// sim: 32x32 output tile per block, 2x2 register blocking per thread.
__global__ __launch_bounds__(256) void sim_kernel(
    const float* __restrict__ q, const float* __restrict__ k,
    float* __restrict__ sim)
{
    __shared__ float qs[32][132];
    __shared__ float ks[32][132];
    int tid = threadIdx.x;
    int bx = blockIdx.x;
    int b  = bx / (12 * 12);
    int r  = bx % (12 * 12);
    int lt = r / 12, st = r % 12;
    int tl = tid >> 4, ts = tid & 15;
    const float* qb = q + (b * Lq + lt * 32) * Dd;
    const float* kb = k + (b * Sk + st * 32) * Dd;
    float a00 = 0.f, a01 = 0.f, a10 = 0.f, a11 = 0.f;
    for (int c = 0; c < Dd; c += 128) {
        __syncthreads();
        for (int i = tid; i < 1024; i += 256) {     // 32 rows x 32 float4
            int row = i >> 5;
            int c4  = (i & 31) << 2;
            *reinterpret_cast<float4*>(&qs[row][c4]) =
                *reinterpret_cast<const float4*>(qb + row * Dd + c + c4);
            *reinterpret_cast<float4*>(&ks[row][c4]) =
                *reinterpret_cast<const float4*>(kb + row * Dd + c + c4);
        }
        __syncthreads();
#pragma unroll 4
        for (int dd = 0; dd < 128; ++dd) {
            float q0 = qs[tl][dd],      q1 = qs[tl + 16][dd];
            float k0 = ks[ts][dd],      k1 = ks[ts + 16][dd];
            a00 = fmaf(q0, k0, a00); a01 = fmaf(q0, k1, a01);
            a10 = fmaf(q1, k0, a10); a11 = fmaf(q1, k1, a11);
        }
    }
    const float sc = 0.04419417382415922f;          // 1/sqrt(512)
    int l0 = lt * 32 + tl, s0 = st * 32 + ts;
    sim[(b * Lq + l0)      * Sk + s0]      = a00 * sc;
    sim[(b * Lq + l0)      * Sk + s0 + 16] = a01 * sc;
    sim[(b * Lq + l0 + 16) * Sk + s0]      = a10 * sc;
    sim[(b * Lq + l0 + 16) * Sk + s0 + 16] = a11 * sc;
}

// ---------------------------------------------------------------------------
// main: per (b,l,s) one pass over H -> threshold -> gumbel decision;
// flag borderline |t|<1e-3 for f64 cleanup.
__global__ __launch_bounds__(256) void main_kernel(
    const float* __restrict__ hq, const float* __restrict__ hk,
    const float* __restrict__ sim, const float* __restrict__ gam,
    const float* __restrict__ W2, const float* __restrict__ scal,
    const float* __restrict__ gu, float* __restrict__ out,
    int* __restrict__ cnt, int* __restrict__ list)
{
    __shared__ float hq_t[16][257];
    __shared__ float hk_t[16][257];
    __shared__ float gw_s[256];
    int tid = threadIdx.x;
    int bx = blockIdx.x;
    int b  = bx / (24 * 24);
    int r  = bx % (24 * 24);
    int lt = r / 24, st = r % 24;

    const float* hqb = hq + (b * Lq + lt * 16) * Hh;
    const float* hkb = hk + (b * Sk + st * 16) * Hh;
#pragma unroll
    for (int kk = 0; kk < 16; ++kk) {
        hq_t[kk][tid] = hqb[kk * Hh + tid];
        hk_t[kk][tid] = hkb[kk * Hh + tid];
    }
    gw_s[tid] = gam[tid] * W2[tid];
    __syncthreads();

    int tl = tid >> 4, ts = tid & 15;
    float s1 = 0.f, s2 = 0.f, sw = 0.f;
    for (int h = 0; h < Hh; ++h) {
        float x = hq_t[tl][h] + hk_t[ts][h];
        float y = 0.5f * x * (1.0f + erff(x * 0.70710678118654752f));
        s1 += y;
        s2 = fmaf(y, y, s2);
        sw = fmaf(y, gw_s[h], sw);
    }
    float mu   = s1 * (1.0f / 256.0f);
    float var  = s2 * (1.0f / 256.0f) - mu * mu;
    float rstd = rsqrtf(var + 1e-5f);
    float thr  = rstd * (sw - mu * scal[0]) + scal[1];

    int l = lt * 16 + tl, s = st * 16 + ts;
    int idx = (b * Lq + l) * Sk + s;
    float  sv = sim[idx];
    float2 uv = reinterpret_cast<const float2*>(gu)[idx];
    float u0 = fminf(fmaxf(uv.x, 1e-6f), 1.0f - 1e-6f);
    float u1 = fminf(fmaxf(uv.y, 1e-6f), 1.0f - 1e-6f);
    float g0 = -logf(-logf(u0));
    float g1 = -logf(-logf(u1));
    float t  = 0.2f * (sv - thr) + (g1 - g0);
    out[idx] = t > 0.0f ? 1.0f : 0.0f;
    if (fabsf(t) < 1e-3f) {
        int p = atomicAdd(cnt, 1);
        if (p < LIST_CAP) list[p] = idx;
    }
}

// ---------------------------------------------------------------------------
// cleanup: per flagged item, f64 finish using precomputed f64 projections.
// One fused 4-value tree reduction: {sum y, sum y^2, sum y*gw, sim dot}.
__global__ __launch_bounds__(256) void cleanup_kernel(
    const float* __restrict__ q, const float* __restrict__ k,
    const double* __restrict__ hq_d, const double* __restrict__ hk_d,
    const double* __restrict__ gq_d, const double* __restrict__ gk_d,
    const float* __restrict__ gam, const float* __restrict__ bet,
    const float* __restrict__ W2, const float* __restrict__ b2,
    const float* __restrict__ gu, float* __restrict__ out,
    const int* __restrict__ cnt, const int* __restrict__ list)
{
    __shared__ double s0[256], s1[256], s2[256], s3[256];
    int tid = threadIdx.x;
    int n = *cnt;
    if (n > LIST_CAP) n = LIST_CAP;
    if (n == 0) return;

    double gw = (double)gam[tid] * (double)W2[tid];
    // pre-loop: bconst = sum(beta*W2)+b2, gwsum = sum(gamma*W2)
    s0[tid] = (double)bet[tid] * (double)W2[tid];
    s1[tid] = gw;
    __syncthreads();
    for (int o = 128; o > 0; o >>= 1) {
        if (tid < o) { s0[tid] += s0[tid + o]; s1[tid] += s1[tid + o]; }
        __syncthreads();
    }
    double bconst = s0[0] + (double)b2[0];
    double gwsum  = s1[0];
    __syncthreads();

    for (int it = blockIdx.x; it < n; it += gridDim.x) {
        int idx = list[it];
        int b   = idx / (Lq * Sk);
        int rem = idx % (Lq * Sk);
        int l = rem / Sk, s = rem % Sk;
        double x = (hq_d[(b * Lq + l) * Hh + tid] + gq_d[b * Hh + tid])
                 + (hk_d[(b * Sk + s) * Hh + tid] + gk_d[b * Hh + tid]);
        double y = 0.5 * x * (1.0 + erf(x * 0.70710678118654752440));
        const float* qrow = q + (b * Lq + l) * Dd;
        const float* krow = k + (b * Sk + s) * Dd;
        double sp = (double)qrow[tid] * (double)krow[tid]
                  + (double)qrow[tid + 256] * (double)krow[tid + 256];
        s0[tid] = y; s1[tid] = y * y; s2[tid] = y * gw; s3[tid] = sp;
        __syncthreads();
        for (int o = 128; o > 0; o >>= 1) {
            if (tid < o) {
                s0[tid] += s0[tid + o]; s1[tid] += s1[tid + o];
                s2[tid] += s2[tid + o]; s3[tid] += s3[tid + o];
            }
            __syncthreads();
        }
        if (tid == 0) {
            double mu   = s0[0] * (1.0 / 256.0);
            double var  = s1[0] * (1.0 / 256.0) - mu * mu;
            double rstd = 1.0 / sqrt(var + 1e-5);
            double thr  = rstd * (s2[0] - mu * gwsum) + bconst;
            double simv = s3[0] / 22.627416997969522;   // sqrt(512)
            float2 uv = reinterpret_cast<const float2*>(gu)[idx];
            double u0 = fmin(fmax((double)uv.x, 1e-6), 1.0 - 1e-6);
            double u1 = fmin(fmax((double)uv.y, 1e-6), 1.0 - 1e-6);
            double g0 = -log(-log(u0));
            double g1 = -log(-log(u1));
            double t  = 0.2 * (simv - thr) + (g1 - g0);
            out[idx] = t > 0.0 ? 1.0f : 0.0f;
        }
        __syncthreads();
    }
}

// ---------------------------------------------------------------------------
extern "C" void kernel_launch(void* const* d_in, const int* in_sizes, int n_in,
                              void* d_out, int out_size, void* d_ws, size_t ws_size,
                              hipStream_t stream)
{
    const float* q   = (const float*)d_in[0];
    const float* k   = (const float*)d_in[1];
    const float* qg  = (const float*)d_in[2];
    const float* kg  = (const float*)d_in[3];
    const float* W1  = (const float*)d_in[4];
    const float* b1  = (const float*)d_in[5];
    const float* gam = (const float*)d_in[6];
    const float* bet = (const float*)d_in[7];
    const float* W2  = (const float*)d_in[8];
    const float* b2  = (const float*)d_in[9];
    const float* gu  = (const float*)d_in[10];
    float* out = (float*)d_out;

    char*   ws   = (char*)d_ws;
    double* hq_d = (double*)(ws + HQD_OFF);
    double* hk_d = (double*)(ws + HKD_OFF);
    double* gq_d = (double*)(ws + GQD_OFF);
    double* gk_d = (double*)(ws + GKD_OFF);
    float*  hq   = (float*)(ws + HQ_OFF);
    float*  hk   = (float*)(ws + HK_OFF);
    float*  sim  = (float*)(ws + SIM_OFF);
    float*  scal = (float*)(ws + SCAL_OFF);
    int*    cnt  = (int*)(ws + CNT_OFF);
    int*    list = (int*)(ws + LIST_OFF);

    hipMemsetAsync(cnt, 0, sizeof(int), stream);
    prep_kernel<<<1, 256, 0, stream>>>(gam, bet, W2, b2, scal);
    globald_kernel<<<2 * Bb, 256, 0, stream>>>(qg, kg, W1, b1, gq_d, gk_d);
    projd_kernel<<<2 * Bb * (Lq / PROJ_ROWS), 256, 0, stream>>>(
        q, k, W1, gq_d, gk_d, hq_d, hk_d, hq, hk);
    sim_kernel<<<Bb * 12 * 12, 256, 0, stream>>>(q, k, sim);
    main_kernel<<<Bb * 24 * 24, 256, 0, stream>>>(
        hq, hk, sim, gam, W2, scal, gu, out, cnt, list);
    cleanup_kernel<<<768, 256, 0, stream>>>(
        q, k, hq_d, hk_d, gq_d, gk_d, gam, bet, W2, b2, gu, out, cnt, list);
}

// Round 3
// 200.454 us; speedup vs baseline: 3.1997x; 1.2699x over previous
//
#include <hip/hip_runtime.h>
#include <hip/hip_bf16.h>
#include <math.h>

#define Bb 2
#define Lq 384
#define Sk 384
#define Dd 512
#define Hh 256

#define PROJ_ROWS 8
#define LIST_CAP 65536

// workspace layout (bytes) — f64 regions first for 8B alignment
#define HQD_OFF  0                                   // B*L*H doubles = 1572864
#define HKD_OFF  (HQD_OFF + Bb*Lq*Hh*8)              // B*S*H doubles = 1572864
#define HQ_OFF   (HKD_OFF + Bb*Sk*Hh*8)              // B*L*H floats = 786432
#define HK_OFF   (HQ_OFF + Bb*Lq*Hh*4)               // B*S*H floats
#define SIM_OFF  (HK_OFF + Bb*Sk*Hh*4)               // B*L*S floats = 1179648
#define CNT_OFF  (SIM_OFF + Bb*Lq*Sk*4)              // 1 int
#define LIST_OFF (CNT_OFF + 16)                      // LIST_CAP ints

// ---------------------------------------------------------------------------
// projd: f64 row projections for ALL rows, with the per-(b,tensor) global
// projection folded in (computed redundantly per block — throughput-bound,
// removes the latency-bound globald dispatch). Emits:
//   hq_d = q@Wq + qg@Wqg      (f64, b1 NOT included — added in cleanup in
//   hk_d = k@Wk + kg@Wkg       numpy's (hq+hk)+b1 order)
//   hq   = (float)(hq_d + b1), hk = (float)(hk_d)   (f32 fast path)
__global__ __launch_bounds__(256) void projd_kernel(
    const float* __restrict__ q, const float* __restrict__ k,
    const float* __restrict__ qg, const float* __restrict__ kg,
    const float* __restrict__ W1, const float* __restrict__ b1,
    double* __restrict__ hq_d, double* __restrict__ hk_d,
    float* __restrict__ hq, float* __restrict__ hk)
{
    __shared__ __align__(16) double tile[PROJ_ROWS * Dd];   // 32 KB
    __shared__ __align__(16) double gvd[Dd];                // 4 KB
    int tid = threadIdx.x;
    const int tpb  = Lq / PROJ_ROWS;     // 48
    const int half = Bb * tpb;           // 96
    int bx = blockIdx.x;
    bool isQ = bx < half;
    int bb = isQ ? bx : bx - half;
    int b  = bb / tpb;
    int rt = bb % tpb;
    const float* src = isQ ? q : k;
    const float* gl  = isQ ? qg : kg;
    int woff  = isQ ? 0 : Dd * Hh;
    int woffg = isQ ? 2 * Dd * Hh : 3 * Dd * Hh;
    double* dstd = isQ ? hq_d : hk_d;
    float*  dstf = isQ ? hq : hk;

    int base = (b * Lq + rt * PROJ_ROWS) * Dd;
    for (int i = tid; i < PROJ_ROWS * Dd; i += 256)
        tile[i] = (double)src[base + i];
    for (int i = tid; i < Dd; i += 256)
        gvd[i] = (double)gl[b * Dd + i];
    __syncthreads();

    double acc[PROJ_ROWS];
#pragma unroll
    for (int r = 0; r < PROJ_ROWS; ++r) acc[r] = 0.0;
    double gacc = 0.0;
    for (int d = 0; d < Dd; d += 2) {
        double w0 = (double)W1[woff  + d * Hh + tid];
        double w1 = (double)W1[woff  + (d + 1) * Hh + tid];
        double g0 = (double)W1[woffg + d * Hh + tid];
        double g1 = (double)W1[woffg + (d + 1) * Hh + tid];
        double2 gv = *reinterpret_cast<const double2*>(&gvd[d]);
        gacc = fma(gv.x, g0, gacc);
        gacc = fma(gv.y, g1, gacc);
#pragma unroll
        for (int r = 0; r < PROJ_ROWS; ++r) {
            double2 tv = *reinterpret_cast<const double2*>(&tile[r * Dd + d]);
            acc[r] = fma(tv.x, w0, acc[r]);
            acc[r] = fma(tv.y, w1, acc[r]);
        }
    }
    float b1v = isQ ? b1[tid] : 0.0f;
    int ob = (b * Lq + rt * PROJ_ROWS) * Hh + tid;
#pragma unroll
    for (int r = 0; r < PROJ_ROWS; ++r) {
        double tot = acc[r] + gacc;
        dstd[ob + r * Hh] = tot;
        dstf[ob + r * Hh] = (float)(tot + (double)b1v);
    }
}

// ---------------------------------------------------------------------------
// sim: 32x32 output tile per block, 2x2 register blocking per thread.
__global__ __launch_bounds__(256) void sim_kernel(
    const float* __restrict__ q, const float* __restrict__ k,
    float* __restrict__ sim)
{
    __shared__ float qs[32][132];
    __shared__ float ks[32][132];
    int tid = threadIdx.x;
    int bx = blockIdx.x;
    int b  = bx / (12 * 12);
    int r  = bx % (12 * 12);
    int lt = r / 12, st = r % 12;
    int tl = tid >> 4, ts = tid & 15;
    const float* qb = q + (b * Lq + lt * 32) * Dd;
    const float* kb = k + (b * Sk + st * 32) * Dd;
    float a00 = 0.f, a01 = 0.f, a10 = 0.f, a11 = 0.f;
    for (int c = 0; c < Dd; c += 128) {
        __syncthreads();
        for (int i = tid; i < 1024; i += 256) {     // 32 rows x 32 float4
            int row = i >> 5;
            int c4  = (i & 31) << 2;
            *reinterpret_cast<float4*>(&qs[row][c4]) =
                *reinterpret_cast<const float4*>(qb + row * Dd + c + c4);
            *reinterpret_cast<float4*>(&ks[row][c4]) =
                *reinterpret_cast<const float4*>(kb + row * Dd + c + c4);
        }
        __syncthreads();
#pragma unroll 4
        for (int dd = 0; dd < 128; ++dd) {
            float q0 = qs[tl][dd],      q1 = qs[tl + 16][dd];
            float k0 = ks[ts][dd],      k1 = ks[ts + 16][dd];
            a00 = fmaf(q0, k0, a00); a01 = fmaf(q0, k1, a01);
            a10 = fmaf(q1, k0, a10); a11 = fmaf(q1, k1, a11);
        }
    }
    const float sc = 0.04419417382415922f;          // 1/sqrt(512)
    int l0 = lt * 32 + tl, s0 = st * 32 + ts;
    sim[(b * Lq + l0)      * Sk + s0]      = a00 * sc;
    sim[(b * Lq + l0)      * Sk + s0 + 16] = a01 * sc;
    sim[(b * Lq + l0 + 16) * Sk + s0]      = a10 * sc;
    sim[(b * Lq + l0 + 16) * Sk + s0 + 16] = a11 * sc;
}

// ---------------------------------------------------------------------------
// main: per (b,l,s) one pass over H with branch-free A&S-7.1.26 erf
// (|eps| <= 1.5e-7) -> threshold -> gumbel decision; flag |t|<1e-3.
// Per-block 2-scalar reduction replaces the old prep kernel.
__global__ __launch_bounds__(256) void main_kernel(
    const float* __restrict__ hq, const float* __restrict__ hk,
    const float* __restrict__ sim, const float* __restrict__ gam,
    const float* __restrict__ bet, const float* __restrict__ W2,
    const float* __restrict__ b2, const float* __restrict__ gu,
    float* __restrict__ out, int* __restrict__ cnt, int* __restrict__ list)
{
    __shared__ __align__(16) float hq_t[16][258];
    __shared__ __align__(16) float hk_t[16][258];
    __shared__ __align__(16) float gw_s[256];
    __shared__ float2 red[256];
    int tid = threadIdx.x;
    int bx = blockIdx.x;
    int b  = bx / (24 * 24);
    int r  = bx % (24 * 24);
    int lt = r / 24, st = r % 24;

    const float* hqb = hq + (b * Lq + lt * 16) * Hh;
    const float* hkb = hk + (b * Sk + st * 16) * Hh;
#pragma unroll
    for (int kk = 0; kk < 16; ++kk) {
        hq_t[kk][tid] = hqb[kk * Hh + tid];
        hk_t[kk][tid] = hkb[kk * Hh + tid];
    }
    float w2v = W2[tid];
    float gwv = gam[tid] * w2v;
    gw_s[tid] = gwv;
    red[tid]  = make_float2(gwv, bet[tid] * w2v);
    __syncthreads();
    for (int o = 128; o > 0; o >>= 1) {
        if (tid < o) {
            red[tid].x += red[tid + o].x;
            red[tid].y += red[tid + o].y;
        }
        __syncthreads();
    }
    float gwsum  = red[0].x;
    float bconst = red[0].y + b2[0];

    const float C1  = 0.70710678118654752f;
    const float Pp  = 0.3275911f;
    const float A1f = 0.254829592f, A2f = -0.284496736f, A3f = 1.421413741f,
                A4f = -1.453152027f, A5f = 1.061405429f;
    const float NL2E = -1.442695040888963f;

    int tl = tid >> 4, ts = tid & 15;
    float s1 = 0.f, s2 = 0.f, sw = 0.f;
#pragma unroll 4
    for (int h2 = 0; h2 < 128; ++h2) {
        float2 hqv = *reinterpret_cast<const float2*>(&hq_t[tl][2 * h2]);
        float2 hkv = *reinterpret_cast<const float2*>(&hk_t[ts][2 * h2]);
        float2 gw2 = *reinterpret_cast<const float2*>(&gw_s[2 * h2]);
#pragma unroll
        for (int e = 0; e < 2; ++e) {
            float x  = (e == 0) ? (hqv.x + hkv.x) : (hqv.y + hkv.y);
            float gw = (e == 0) ? gw2.x : gw2.y;
            float ax = fabsf(x);
            float a  = C1 * ax;
            float dd = fmaf(Pp, a, 1.0f);
            float tt = __builtin_amdgcn_rcpf(dd);
            float ex = __builtin_amdgcn_exp2f(a * a * NL2E);
            float s  = fmaf(A5f, tt, A4f);
            s = fmaf(s, tt, A3f);
            s = fmaf(s, tt, A2f);
            s = fmaf(s, tt, A1f);
            s = s * tt;
            float E = fmaf(-s, ex, 1.0f);            // erf(|x|/sqrt2)
            float y = fmaf(0.5f * ax, E, 0.5f * x);  // gelu(x)
            s1 += y;
            s2 = fmaf(y, y, s2);
            sw = fmaf(y, gw, sw);
        }
    }
    float mu   = s1 * (1.0f / 256.0f);
    float var  = s2 * (1.0f / 256.0f) - mu * mu;
    float rstd = rsqrtf(var + 1e-5f);
    float thr  = rstd * (sw - mu * gwsum) + bconst;

    int l = lt * 16 + tl, s = st * 16 + ts;
    int idx = (b * Lq + l) * Sk + s;
    float  sv = sim[idx];
    float2 uv = reinterpret_cast<const float2*>(gu)[idx];
    float u0 = fminf(fmaxf(uv.x, 1e-6f), 1.0f - 1e-6f);
    float u1 = fminf(fmaxf(uv.y, 1e-6f), 1.0f - 1e-6f);
    float g0 = -logf(-logf(u0));
    float g1 = -logf(-logf(u1));
    float t  = 0.2f * (sv - thr) + (g1 - g0);
    out[idx] = t > 0.0f ? 1.0f : 0.0f;
    if (fabsf(t) < 1e-3f) {
        int p = atomicAdd(cnt, 1);
        if (p < LIST_CAP) list[p] = idx;
    }
}

// ---------------------------------------------------------------------------
// cleanup: per flagged item, f64 finish using precomputed f64 projections.
// x = (hq_d + hk_d) + b1  — numpy's order. One fused 4-value tree reduction.
__global__ __launch_bounds__(256) void cleanup_kernel(
    const float* __restrict__ q, const float* __restrict__ k,
    const double* __restrict__ hq_d, const double* __restrict__ hk_d,
    const float* __restrict__ b1,
    const float* __restrict__ gam, const float* __restrict__ bet,
    const float* __restrict__ W2, const float* __restrict__ b2,
    const float* __restrict__ gu, float* __restrict__ out,
    const int* __restrict__ cnt, const int* __restrict__ list)
{
    __shared__ double s0[256], s1[256], s2[256], s3[256];
    int tid = threadIdx.x;
    int n = *cnt;
    if (n > LIST_CAP) n = LIST_CAP;
    if (n == 0) return;

    double gw  = (double)gam[tid] * (double)W2[tid];
    double b1d = (double)b1[tid];
    s0[tid] = (double)bet[tid] * (double)W2[tid];
    s1[tid] = gw;
    __syncthreads();
    for (int o = 128; o > 0; o >>= 1) {
        if (tid < o) { s0[tid] += s0[tid + o]; s1[tid] += s1[tid + o]; }
        __syncthreads();
    }
    double bconst = s0[0] + (double)b2[0];
    double gwsum  = s1[0];
    __syncthreads();

    for (int it = blockIdx.x; it < n; it += gridDim.x) {
        int idx = list[it];
        int b   = idx / (Lq * Sk);
        int rem = idx % (Lq * Sk);
        int l = rem / Sk, s = rem % Sk;
        double x = (hq_d[(b * Lq + l) * Hh + tid]
                  + hk_d[(b * Sk + s) * Hh + tid]) + b1d;
        double y = 0.5 * x * (1.0 + erf(x * 0.70710678118654752440));
        const float* qrow = q + (b * Lq + l) * Dd;
        const float* krow = k + (b * Sk + s) * Dd;
        double sp = (double)qrow[tid] * (double)krow[tid]
                  + (double)qrow[tid + 256] * (double)krow[tid + 256];
        s0[tid] = y; s1[tid] = y * y; s2[tid] = y * gw; s3[tid] = sp;
        __syncthreads();
        for (int o = 128; o > 0; o >>= 1) {
            if (tid < o) {
                s0[tid] += s0[tid + o]; s1[tid] += s1[tid + o];
                s2[tid] += s2[tid + o]; s3[tid] += s3[tid + o];
            }
            __syncthreads();
        }
        if (tid == 0) {
            double mu   = s0[0] * (1.0 / 256.0);
            double var  = s1[0] * (1.0 / 256.0) - mu * mu;
            double rstd = 1.0 / sqrt(var + 1e-5);
            double thr  = rstd * (s2[0] - mu * gwsum) + bconst;
            double simv = s3[0] / 22.627416997969522;   // sqrt(512)
            float2 uv = reinterpret_cast<const float2*>(gu)[idx];
            double u0 = fmin(fmax((double)uv.x, 1e-6), 1.0 - 1e-6);
            double u1 = fmin(fmax((double)uv.y, 1e-6), 1.0 - 1e-6);
            double g0 = -log(-log(u0));
            double g1 = -log(-log(u1));
            double t  = 0.2 * (simv - thr) + (g1 - g0);
            out[idx] = t > 0.0 ? 1.0f : 0.0f;
        }
        __syncthreads();
    }
}

// ---------------------------------------------------------------------------
extern "C" void kernel_launch(void* const* d_in, const int* in_sizes, int n_in,
                              void* d_out, int out_size, void* d_ws, size_t ws_size,
                              hipStream_t stream)
{
    const float* q   = (const float*)d_in[0];
    const float* k   = (const float*)d_in[1];
    const float* qg  = (const float*)d_in[2];
    const float* kg  = (const float*)d_in[3];
    const float* W1  = (const float*)d_in[4];
    const float* b1  = (const float*)d_in[5];
    const float* gam = (const float*)d_in[6];
    const float* bet = (const float*)d_in[7];
    const float* W2  = (const float*)d_in[8];
    const float* b2  = (const float*)d_in[9];
    const float* gu  = (const float*)d_in[10];
    float* out = (float*)d_out;

    char*   ws   = (char*)d_ws;
    double* hq_d = (double*)(ws + HQD_OFF);
    double* hk_d = (double*)(ws + HKD_OFF);
    float*  hq   = (float*)(ws + HQ_OFF);
    float*  hk   = (float*)(ws + HK_OFF);
    float*  sim  = (float*)(ws + SIM_OFF);
    int*    cnt  = (int*)(ws + CNT_OFF);
    int*    list = (int*)(ws + LIST_OFF);

    hipMemsetAsync(cnt, 0, sizeof(int), stream);
    projd_kernel<<<2 * Bb * (Lq / PROJ_ROWS), 256, 0, stream>>>(
        q, k, qg, kg, W1, b1, hq_d, hk_d, hq, hk);
    sim_kernel<<<Bb * 12 * 12, 256, 0, stream>>>(q, k, sim);
    main_kernel<<<Bb * 24 * 24, 256, 0, stream>>>(
        hq, hk, sim, gam, bet, W2, b2, gu, out, cnt, list);
    cleanup_kernel<<<768, 256, 0, stream>>>(
        q, k, hq_d, hk_d, b1, gam, bet, W2, b2, gu, out, cnt, list);
}

// Round 4
// 175.222 us; speedup vs baseline: 3.6604x; 1.1440x over previous
//
#include <hip/hip_runtime.h>
#include <hip/hip_bf16.h>
#include <math.h>

#define Bb 2
#define Lq 384
#define Sk 384
#define Dd 512
#define Hh 256

#define PROJ_ROWS 2
#define LIST_CAP 65536

// workspace layout (bytes) — f64 regions first for 8B alignment
#define HQD_OFF  0                                   // B*L*H doubles = 1572864
#define HKD_OFF  (HQD_OFF + Bb*Lq*Hh*8)              // B*S*H doubles = 1572864
#define GQD_OFF  (HKD_OFF + Bb*Sk*Hh*8)              // B*H doubles = 4096
#define GKD_OFF  (GQD_OFF + Bb*Hh*8)                 // B*H doubles = 4096
#define HQ_OFF   (GKD_OFF + Bb*Hh*8)                 // B*L*H floats = 786432
#define HK_OFF   (HQ_OFF + Bb*Lq*Hh*4)               // B*S*H floats
#define SIM0_OFF (HK_OFF + Bb*Sk*Hh*4)               // B*L*S floats = 1179648
#define SIM1_OFF (SIM0_OFF + Bb*Lq*Sk*4)             // B*L*S floats
#define CNT_OFF  (SIM1_OFF + Bb*Lq*Sk*4)             // 1 int
#define LIST_OFF (CNT_OFF + 16)                      // LIST_CAP ints

// ---------------------------------------------------------------------------
// globald: gq_d[b,h] = qg[b,:]@Wqg (f64), gk_d[b,h] = kg[b,:]@Wkg.
// 16 blocks: (hchunk,b,tensor); thread = 64 h x 4 d-quarters; ILP-4 chains.
__global__ __launch_bounds__(256) void globald_kernel(
    const float* __restrict__ qg, const float* __restrict__ kg,
    const float* __restrict__ W1,
    double* __restrict__ gq_d, double* __restrict__ gk_d)
{
    __shared__ double red[64][5];
    int bx  = blockIdx.x;
    int isK = bx & 1;
    int b   = (bx >> 1) & 1;
    int hc  = bx >> 2;                  // 0..3
    int tid = threadIdx.x;
    int hl  = tid >> 2;                 // 0..63
    int dp  = tid & 3;                  // 0..3
    int h   = hc * 64 + hl;
    const float* gv = (isK ? kg : qg) + b * Dd;
    const float* wp = W1 + (isK ? 3 : 2) * Dd * Hh + h;
    int d0 = dp * 128;
    double a0 = 0, a1 = 0, a2 = 0, a3 = 0;
    for (int i = 0; i < 128; i += 4) {
        int d = d0 + i;
        a0 = fma((double)gv[d + 0], (double)wp[(d + 0) * Hh], a0);
        a1 = fma((double)gv[d + 1], (double)wp[(d + 1) * Hh], a1);
        a2 = fma((double)gv[d + 2], (double)wp[(d + 2) * Hh], a2);
        a3 = fma((double)gv[d + 3], (double)wp[(d + 3) * Hh], a3);
    }
    red[hl][dp] = ((a0 + a1) + (a2 + a3));
    __syncthreads();
    if (dp == 0) {
        double s = (red[hl][0] + red[hl][1]) + (red[hl][2] + red[hl][3]);
        (isK ? gk_d : gq_d)[b * Hh + h] = s;
    }
}

// ---------------------------------------------------------------------------
// projd: f64 row projections, 2 rows/block (grid 768 = 3 blocks/CU).
// f32 LDS tile, float4 broadcast reads, per-value cvt in VALU.
//   hq_d = q@Wq + gq_d   (f64; b1 NOT included — cleanup adds it)
//   hq   = (float)(hq_d + b1)      [k-side: no b1]
__global__ __launch_bounds__(256) void projd_kernel(
    const float* __restrict__ q, const float* __restrict__ k,
    const float* __restrict__ W1, const float* __restrict__ b1,
    const double* __restrict__ gq_d, const double* __restrict__ gk_d,
    double* __restrict__ hq_d, double* __restrict__ hk_d,
    float* __restrict__ hq, float* __restrict__ hk)
{
    __shared__ __align__(16) float tile[PROJ_ROWS][Dd];   // 4 KB
    int tid = threadIdx.x;
    const int tpb  = Lq / PROJ_ROWS;     // 192
    const int half = Bb * tpb;           // 384
    int bx = blockIdx.x;
    bool isQ = bx < half;
    int bb = isQ ? bx : bx - half;
    int b  = bb / tpb;
    int rt = bb % tpb;
    const float*  src = isQ ? q : k;
    const double* gl  = isQ ? gq_d : gk_d;
    int woff = isQ ? 0 : Dd * Hh;
    double* dstd = isQ ? hq_d : hk_d;
    float*  dstf = isQ ? hq : hk;

    int base = (b * Lq + rt * PROJ_ROWS) * Dd;
    // stage 2 rows = 1024 floats: one float4 per thread
    *reinterpret_cast<float4*>(&tile[0][0] + tid * 4) =
        *reinterpret_cast<const float4*>(src + base + tid * 4);
    double gd = gl[b * Hh + tid];
    __syncthreads();

    const float* wp = W1 + woff + tid;
    double acc0 = 0.0, acc1 = 0.0;
    for (int d4 = 0; d4 < Dd; d4 += 4) {
        double w0 = (double)wp[(d4 + 0) * Hh];
        double w1 = (double)wp[(d4 + 1) * Hh];
        double w2 = (double)wp[(d4 + 2) * Hh];
        double w3 = (double)wp[(d4 + 3) * Hh];
        float4 t0 = *reinterpret_cast<const float4*>(&tile[0][d4]);
        float4 t1 = *reinterpret_cast<const float4*>(&tile[1][d4]);
        acc0 = fma((double)t0.x, w0, acc0);
        acc0 = fma((double)t0.y, w1, acc0);
        acc0 = fma((double)t0.z, w2, acc0);
        acc0 = fma((double)t0.w, w3, acc0);
        acc1 = fma((double)t1.x, w0, acc1);
        acc1 = fma((double)t1.y, w1, acc1);
        acc1 = fma((double)t1.z, w2, acc1);
        acc1 = fma((double)t1.w, w3, acc1);
    }
    double b1d = isQ ? (double)b1[tid] : 0.0;
    int ob = (b * Lq + rt * PROJ_ROWS) * Hh + tid;
    double tot0 = acc0 + gd, tot1 = acc1 + gd;
    dstd[ob]      = tot0;
    dstd[ob + Hh] = tot1;
    dstf[ob]      = (float)(tot0 + b1d);
    dstf[ob + Hh] = (float)(tot1 + b1d);
}

// ---------------------------------------------------------------------------
// sim: 32x32 tile, 2x2 per thread, float4 inner reads, K split in 2 halves
// (grid 576); partials to sim0/sim1, main sums them.
__global__ __launch_bounds__(256) void sim_kernel(
    const float* __restrict__ q, const float* __restrict__ k,
    float* __restrict__ sim01)
{
    __shared__ __align__(16) float qs[32][132];
    __shared__ __align__(16) float ks[32][132];
    int tid = threadIdx.x;
    int bx = blockIdx.x;
    int kc = (bx >= Bb * 144) ? 1 : 0;
    int r  = bx - kc * Bb * 144;
    int b  = r / 144;  r %= 144;
    int lt = r / 12, st = r % 12;
    int tl = tid >> 4, ts = tid & 15;
    const float* qb = q + (b * Lq + lt * 32) * Dd;
    const float* kb = k + (b * Sk + st * 32) * Dd;
    float a00 = 0.f, a01 = 0.f, a10 = 0.f, a11 = 0.f;
    for (int c = kc * 256; c < kc * 256 + 256; c += 128) {
        __syncthreads();
        for (int i = tid; i < 1024; i += 256) {     // 32 rows x 32 float4
            int row = i >> 5;
            int c4  = (i & 31) << 2;
            *reinterpret_cast<float4*>(&qs[row][c4]) =
                *reinterpret_cast<const float4*>(qb + row * Dd + c + c4);
            *reinterpret_cast<float4*>(&ks[row][c4]) =
                *reinterpret_cast<const float4*>(kb + row * Dd + c + c4);
        }
        __syncthreads();
#pragma unroll 2
        for (int dd = 0; dd < 128; dd += 4) {
            float4 q0 = *reinterpret_cast<const float4*>(&qs[tl][dd]);
            float4 q1 = *reinterpret_cast<const float4*>(&qs[tl + 16][dd]);
            float4 k0 = *reinterpret_cast<const float4*>(&ks[ts][dd]);
            float4 k1 = *reinterpret_cast<const float4*>(&ks[ts + 16][dd]);
            a00 = fmaf(q0.x, k0.x, a00); a00 = fmaf(q0.y, k0.y, a00);
            a00 = fmaf(q0.z, k0.z, a00); a00 = fmaf(q0.w, k0.w, a00);
            a01 = fmaf(q0.x, k1.x, a01); a01 = fmaf(q0.y, k1.y, a01);
            a01 = fmaf(q0.z, k1.z, a01); a01 = fmaf(q0.w, k1.w, a01);
            a10 = fmaf(q1.x, k0.x, a10); a10 = fmaf(q1.y, k0.y, a10);
            a10 = fmaf(q1.z, k0.z, a10); a10 = fmaf(q1.w, k0.w, a10);
            a11 = fmaf(q1.x, k1.x, a11); a11 = fmaf(q1.y, k1.y, a11);
            a11 = fmaf(q1.z, k1.z, a11); a11 = fmaf(q1.w, k1.w, a11);
        }
    }
    const float sc = 0.04419417382415922f;          // 1/sqrt(512)
    float* dst = sim01 + kc * (Bb * Lq * Sk);
    int l0 = lt * 32 + tl, s0 = st * 32 + ts;
    dst[(b * Lq + l0)      * Sk + s0]      = a00 * sc;
    dst[(b * Lq + l0)      * Sk + s0 + 16] = a01 * sc;
    dst[(b * Lq + l0 + 16) * Sk + s0]      = a10 * sc;
    dst[(b * Lq + l0 + 16) * Sk + s0 + 16] = a11 * sc;
}

// ---------------------------------------------------------------------------
// main: per (b,l,s) one pass over H with branch-free A&S-7.1.26 erf
// (|eps| <= 1.5e-7) -> threshold -> gumbel decision; flag |t|<1e-3.
__global__ __launch_bounds__(256) void main_kernel(
    const float* __restrict__ hq, const float* __restrict__ hk,
    const float* __restrict__ sim0, const float* __restrict__ sim1,
    const float* __restrict__ gam, const float* __restrict__ bet,
    const float* __restrict__ W2, const float* __restrict__ b2,
    const float* __restrict__ gu, float* __restrict__ out,
    int* __restrict__ cnt, int* __restrict__ list)
{
    __shared__ __align__(16) float hq_t[16][258];
    __shared__ __align__(16) float hk_t[16][258];
    __shared__ __align__(16) float gw_s[256];
    __shared__ float2 red[256];
    int tid = threadIdx.x;
    int bx = blockIdx.x;
    int b  = bx / (24 * 24);
    int r  = bx % (24 * 24);
    int lt = r / 24, st = r % 24;

    const float* hqb = hq + (b * Lq + lt * 16) * Hh;
    const float* hkb = hk + (b * Sk + st * 16) * Hh;
#pragma unroll
    for (int kk = 0; kk < 16; ++kk) {
        hq_t[kk][tid] = hqb[kk * Hh + tid];
        hk_t[kk][tid] = hkb[kk * Hh + tid];
    }
    float w2v = W2[tid];
    float gwv = gam[tid] * w2v;
    gw_s[tid] = gwv;
    red[tid]  = make_float2(gwv, bet[tid] * w2v);
    __syncthreads();
    for (int o = 128; o > 0; o >>= 1) {
        if (tid < o) {
            red[tid].x += red[tid + o].x;
            red[tid].y += red[tid + o].y;
        }
        __syncthreads();
    }
    float gwsum  = red[0].x;
    float bconst = red[0].y + b2[0];

    const float C1  = 0.70710678118654752f;
    const float Pp  = 0.3275911f;
    const float A1f = 0.254829592f, A2f = -0.284496736f, A3f = 1.421413741f,
                A4f = -1.453152027f, A5f = 1.061405429f;
    const float NL2E = -1.442695040888963f;

    int tl = tid >> 4, ts = tid & 15;
    float s1 = 0.f, s2 = 0.f, sw = 0.f;
#pragma unroll 4
    for (int h2 = 0; h2 < 128; ++h2) {
        float2 hqv = *reinterpret_cast<const float2*>(&hq_t[tl][2 * h2]);
        float2 hkv = *reinterpret_cast<const float2*>(&hk_t[ts][2 * h2]);
        float2 gw2 = *reinterpret_cast<const float2*>(&gw_s[2 * h2]);
#pragma unroll
        for (int e = 0; e < 2; ++e) {
            float x  = (e == 0) ? (hqv.x + hkv.x) : (hqv.y + hkv.y);
            float gw = (e == 0) ? gw2.x : gw2.y;
            float ax = fabsf(x);
            float a  = C1 * ax;
            float dd = fmaf(Pp, a, 1.0f);
            float tt = __builtin_amdgcn_rcpf(dd);
            float ex = __builtin_amdgcn_exp2f(a * a * NL2E);
            float s  = fmaf(A5f, tt, A4f);
            s = fmaf(s, tt, A3f);
            s = fmaf(s, tt, A2f);
            s = fmaf(s, tt, A1f);
            s = s * tt;
            float E = fmaf(-s, ex, 1.0f);            // erf(|x|/sqrt2)
            float y = fmaf(0.5f * ax, E, 0.5f * x);  // gelu(x)
            s1 += y;
            s2 = fmaf(y, y, s2);
            sw = fmaf(y, gw, sw);
        }
    }
    float mu   = s1 * (1.0f / 256.0f);
    float var  = s2 * (1.0f / 256.0f) - mu * mu;
    float rstd = rsqrtf(var + 1e-5f);
    float thr  = rstd * (sw - mu * gwsum) + bconst;

    int l = lt * 16 + tl, s = st * 16 + ts;
    int idx = (b * Lq + l) * Sk + s;
    float  sv = sim0[idx] + sim1[idx];
    float2 uv = reinterpret_cast<const float2*>(gu)[idx];
    float u0 = fminf(fmaxf(uv.x, 1e-6f), 1.0f - 1e-6f);
    float u1 = fminf(fmaxf(uv.y, 1e-6f), 1.0f - 1e-6f);
    float g0 = -logf(-logf(u0));
    float g1 = -logf(-logf(u1));
    float t  = 0.2f * (sv - thr) + (g1 - g0);
    out[idx] = t > 0.0f ? 1.0f : 0.0f;
    if (fabsf(t) < 1e-3f) {
        int p = atomicAdd(cnt, 1);
        if (p < LIST_CAP) list[p] = idx;
    }
}

// ---------------------------------------------------------------------------
// cleanup: per flagged item, f64 finish using precomputed f64 projections.
// x = (hq_d + hk_d) + b1. One fused 4-value tree reduction.
__global__ __launch_bounds__(256) void cleanup_kernel(
    const float* __restrict__ q, const float* __restrict__ k,
    const double* __restrict__ hq_d, const double* __restrict__ hk_d,
    const float* __restrict__ b1,
    const float* __restrict__ gam, const float* __restrict__ bet,
    const float* __restrict__ W2, const float* __restrict__ b2,
    const float* __restrict__ gu, float* __restrict__ out,
    const int* __restrict__ cnt, const int* __restrict__ list)
{
    __shared__ double s0[256], s1[256], s2[256], s3[256];
    int tid = threadIdx.x;
    int n = *cnt;
    if (n > LIST_CAP) n = LIST_CAP;
    if (n == 0) return;

    double gw  = (double)gam[tid] * (double)W2[tid];
    double b1d = (double)b1[tid];
    s0[tid] = (double)bet[tid] * (double)W2[tid];
    s1[tid] = gw;
    __syncthreads();
    for (int o = 128; o > 0; o >>= 1) {
        if (tid < o) { s0[tid] += s0[tid + o]; s1[tid] += s1[tid + o]; }
        __syncthreads();
    }
    double bconst = s0[0] + (double)b2[0];
    double gwsum  = s1[0];
    __syncthreads();

    for (int it = blockIdx.x; it < n; it += gridDim.x) {
        int idx = list[it];
        int b   = idx / (Lq * Sk);
        int rem = idx % (Lq * Sk);
        int l = rem / Sk, s = rem % Sk;
        double x = (hq_d[(b * Lq + l) * Hh + tid]
                  + hk_d[(b * Sk + s) * Hh + tid]) + b1d;
        double y = 0.5 * x * (1.0 + erf(x * 0.70710678118654752440));
        const float* qrow = q + (b * Lq + l) * Dd;
        const float* krow = k + (b * Sk + s) * Dd;
        double sp = (double)qrow[tid] * (double)krow[tid]
                  + (double)qrow[tid + 256] * (double)krow[tid + 256];
        s0[tid] = y; s1[tid] = y * y; s2[tid] = y * gw; s3[tid] = sp;
        __syncthreads();
        for (int o = 128; o > 0; o >>= 1) {
            if (tid < o) {
                s0[tid] += s0[tid + o]; s1[tid] += s1[tid + o];
                s2[tid] += s2[tid + o]; s3[tid] += s3[tid + o];
            }
            __syncthreads();
        }
        if (tid == 0) {
            double mu   = s0[0] * (1.0 / 256.0);
            double var  = s1[0] * (1.0 / 256.0) - mu * mu;
            double rstd = 1.0 / sqrt(var + 1e-5);
            double thr  = rstd * (s2[0] - mu * gwsum) + bconst;
            double simv = s3[0] / 22.627416997969522;   // sqrt(512)
            float2 uv = reinterpret_cast<const float2*>(gu)[idx];
            double u0 = fmin(fmax((double)uv.x, 1e-6), 1.0 - 1e-6);
            double u1 = fmin(fmax((double)uv.y, 1e-6), 1.0 - 1e-6);
            double g0 = -log(-log(u0));
            double g1 = -log(-log(u1));
            double t  = 0.2 * (simv - thr) + (g1 - g0);
            out[idx] = t > 0.0 ? 1.0f : 0.0f;
        }
        __syncthreads();
    }
}

// ---------------------------------------------------------------------------
extern "C" void kernel_launch(void* const* d_in, const int* in_sizes, int n_in,
                              void* d_out, int out_size, void* d_ws, size_t ws_size,
                              hipStream_t stream)
{
    const float* q   = (const float*)d_in[0];
    const float* k   = (const float*)d_in[1];
    const float* qg  = (const float*)d_in[2];
    const float* kg  = (const float*)d_in[3];
    const float* W1  = (const float*)d_in[4];
    const float* b1  = (const float*)d_in[5];
    const float* gam = (const float*)d_in[6];
    const float* bet = (const float*)d_in[7];
    const float* W2  = (const float*)d_in[8];
    const float* b2  = (const float*)d_in[9];
    const float* gu  = (const float*)d_in[10];
    float* out = (float*)d_out;

    char*   ws   = (char*)d_ws;
    double* hq_d = (double*)(ws + HQD_OFF);
    double* hk_d = (double*)(ws + HKD_OFF);
    double* gq_d = (double*)(ws + GQD_OFF);
    double* gk_d = (double*)(ws + GKD_OFF);
    float*  hq   = (float*)(ws + HQ_OFF);
    float*  hk   = (float*)(ws + HK_OFF);
    float*  sim0 = (float*)(ws + SIM0_OFF);
    float*  sim1 = (float*)(ws + SIM1_OFF);
    int*    cnt  = (int*)(ws + CNT_OFF);
    int*    list = (int*)(ws + LIST_OFF);

    hipMemsetAsync(cnt, 0, sizeof(int), stream);
    globald_kernel<<<16, 256, 0, stream>>>(qg, kg, W1, gq_d, gk_d);
    projd_kernel<<<2 * Bb * (Lq / PROJ_ROWS), 256, 0, stream>>>(
        q, k, W1, b1, gq_d, gk_d, hq_d, hk_d, hq, hk);
    sim_kernel<<<2 * Bb * 144, 256, 0, stream>>>(q, k, sim0);
    main_kernel<<<Bb * 24 * 24, 256, 0, stream>>>(
        hq, hk, sim0, sim1, gam, bet, W2, b2, gu, out, cnt, list);
    cleanup_kernel<<<768, 256, 0, stream>>>(
        q, k, hq_d, hk_d, b1, gam, bet, W2, b2, gu, out, cnt, list);
}

// Round 7
// 167.570 us; speedup vs baseline: 3.8276x; 1.0457x over previous
//
#include <hip/hip_runtime.h>
#include <hip/hip_bf16.h>
#include <math.h>

#define Bb 2
#define Lq 384
#define Sk 384
#define Dd 512
#define Hh 256

#define LIST_CAP 65536

// workspace layout (bytes) — f64 regions first for 8B alignment
#define HQD_OFF  0                                   // B*L*H doubles = 1572864
#define HKD_OFF  (HQD_OFF + Bb*Lq*Hh*8)              // B*S*H doubles = 1572864
#define GQD_OFF  (HKD_OFF + Bb*Sk*Hh*8)              // B*H doubles
#define GKD_OFF  (GQD_OFF + Bb*Hh*8)
#define HQ_OFF   (GKD_OFF + Bb*Hh*8)                 // B*L*H floats = 786432
#define HK_OFF   (HQ_OFF + Bb*Lq*Hh*4)               // B*S*H floats
#define SIM0_OFF (HK_OFF + Bb*Sk*Hh*4)               // B*L*S floats = 1179648
#define SIM1_OFF (SIM0_OFF + Bb*Lq*Sk*4)             // B*L*S floats
#define SCAL_OFF (SIM1_OFF + Bb*Lq*Sk*4)             // 2 floats
#define GW_OFF   (SCAL_OFF + 64)                     // 256 floats
#define CNT_OFF  (GW_OFF + 1024)                     // 1 int
#define LIST_OFF (CNT_OFF + 64)                      // LIST_CAP ints

// ---------------------------------------------------------------------------
// smalls: bx<16 -> globald (f64 global-vector projections);
//         bx==16 -> gw[h]=gam*W2, scal={gwsum, bconst} (f32 for main).
__global__ __launch_bounds__(256) void smalls_kernel(
    const float* __restrict__ qg, const float* __restrict__ kg,
    const float* __restrict__ W1,
    const float* __restrict__ gam, const float* __restrict__ bet,
    const float* __restrict__ W2, const float* __restrict__ b2,
    double* __restrict__ gq_d, double* __restrict__ gk_d,
    float* __restrict__ gw_out, float* __restrict__ scal)
{
    __shared__ double red[64][5];
    __shared__ float2 red2[256];
    int bx  = blockIdx.x;
    int tid = threadIdx.x;
    if (bx < 16) {
        int isK = bx & 1;
        int b   = (bx >> 1) & 1;
        int hc  = bx >> 2;                  // 0..3
        int hl  = tid >> 2;                 // 0..63
        int dp  = tid & 3;                  // 0..3
        int h   = hc * 64 + hl;
        const float* gv = (isK ? kg : qg) + b * Dd;
        const float* wp = W1 + (isK ? 3 : 2) * Dd * Hh + h;
        int d0 = dp * 128;
        double a0 = 0, a1 = 0, a2 = 0, a3 = 0;
        for (int i = 0; i < 128; i += 4) {
            int d = d0 + i;
            a0 = fma((double)gv[d + 0], (double)wp[(d + 0) * Hh], a0);
            a1 = fma((double)gv[d + 1], (double)wp[(d + 1) * Hh], a1);
            a2 = fma((double)gv[d + 2], (double)wp[(d + 2) * Hh], a2);
            a3 = fma((double)gv[d + 3], (double)wp[(d + 3) * Hh], a3);
        }
        red[hl][dp] = ((a0 + a1) + (a2 + a3));
        __syncthreads();
        if (dp == 0) {
            double s = (red[hl][0] + red[hl][1]) + (red[hl][2] + red[hl][3]);
            (isK ? gk_d : gq_d)[b * Hh + h] = s;
        }
    } else {
        float w2v = W2[tid];
        float gwv = gam[tid] * w2v;
        gw_out[tid] = gwv;
        red2[tid] = make_float2(gwv, bet[tid] * w2v);
        __syncthreads();
        for (int o = 128; o > 0; o >>= 1) {
            if (tid < o) {
                red2[tid].x += red2[tid + o].x;
                red2[tid].y += red2[tid + o].y;
            }
            __syncthreads();
        }
        if (tid == 0) {
            scal[0] = red2[0].x;
            scal[1] = red2[0].y + b2[0];
        }
    }
}

// ---------------------------------------------------------------------------
// projd: 192 blocks x 512 threads. Block = 8 rows of one (tensor,b); thread
// = (h, d-half). W1 read once per 8 rows (98 MB total vs 393 before).
// f64 row projections + f32 fast-path output (global folded; b1 only in f32).
__global__ __launch_bounds__(512) void projd_kernel(
    const float* __restrict__ q, const float* __restrict__ k,
    const float* __restrict__ W1, const float* __restrict__ b1,
    const double* __restrict__ gq_d, const double* __restrict__ gk_d,
    double* __restrict__ hq_d, double* __restrict__ hk_d,
    float* __restrict__ hq, float* __restrict__ hk)
{
    __shared__ __align__(16) float smem[8 * 512];        // 16 KB, aliased
    float  (*tile)[512] = (float (*)[512])smem;
    double (*pbuf)[256] = (double (*)[256])smem;         // alias after compute
    int tid = threadIdx.x;
    int h   = tid & 255;
    int dh  = tid >> 8;                                  // 0/1
    int bx = blockIdx.x;                                 // 0..191
    bool isQ = bx < 96;
    int bb = isQ ? bx : bx - 96;
    int b  = bb / 48;
    int rg = bb % 48;
    const float*  src = isQ ? q : k;
    const double* gl  = isQ ? gq_d : gk_d;
    int woff = isQ ? 0 : Dd * Hh;
    double* dstd = isQ ? hq_d : hk_d;
    float*  dstf = isQ ? hq : hk;

    int base = (b * Lq + rg * 8) * Dd;
    for (int i = tid; i < 1024; i += 512)
        *reinterpret_cast<float4*>(&smem[i * 4]) =
            *reinterpret_cast<const float4*>(src + base + i * 4);
    __syncthreads();

    const float* wp = W1 + woff + (dh * 256) * Hh + h;
    int dbase = dh * 256;
    double acc[8];
#pragma unroll
    for (int r = 0; r < 8; ++r) acc[r] = 0.0;
#pragma unroll 2
    for (int d4 = 0; d4 < 256; d4 += 4) {
        double w0 = (double)wp[(d4 + 0) * Hh];
        double w1 = (double)wp[(d4 + 1) * Hh];
        double w2 = (double)wp[(d4 + 2) * Hh];
        double w3 = (double)wp[(d4 + 3) * Hh];
#pragma unroll
        for (int r = 0; r < 8; ++r) {
            float4 tv = *reinterpret_cast<const float4*>(&tile[r][dbase + d4]);
            acc[r] = fma((double)tv.x, w0, acc[r]);
            acc[r] = fma((double)tv.y, w1, acc[r]);
            acc[r] = fma((double)tv.z, w2, acc[r]);
            acc[r] = fma((double)tv.w, w3, acc[r]);
        }
    }
    __syncthreads();                 // tile reads complete
    if (dh == 1) {
#pragma unroll
        for (int r = 0; r < 8; ++r) pbuf[r][h] = acc[r];
    }
    __syncthreads();
    if (dh == 0) {
        double gd  = gl[b * Hh + h];
        double b1d = isQ ? (double)b1[h] : 0.0;
        int ob = (b * Lq + rg * 8) * Hh + h;
#pragma unroll
        for (int r = 0; r < 8; ++r) {
            double tot = (acc[r] + pbuf[r][h]) + gd;
            dstd[ob + r * Hh] = tot;
            dstf[ob + r * Hh] = (float)(tot + b1d);
        }
    }
}

// ---------------------------------------------------------------------------
// sim: 32x32 tile, 2x2 per thread, float4 inner reads, K split in 2 halves.
__global__ __launch_bounds__(256) void sim_kernel(
    const float* __restrict__ q, const float* __restrict__ k,
    float* __restrict__ sim01)
{
    __shared__ __align__(16) float qs[32][132];
    __shared__ __align__(16) float ks[32][132];
    int tid = threadIdx.x;
    int bx = blockIdx.x;
    int kc = (bx >= Bb * 144) ? 1 : 0;
    int r  = bx - kc * Bb * 144;
    int b  = r / 144;  r %= 144;
    int lt = r / 12, st = r % 12;
    int tl = tid >> 4, ts = tid & 15;
    const float* qb = q + (b * Lq + lt * 32) * Dd;
    const float* kb = k + (b * Sk + st * 32) * Dd;
    float a00 = 0.f, a01 = 0.f, a10 = 0.f, a11 = 0.f;
    for (int c = kc * 256; c < kc * 256 + 256; c += 128) {
        __syncthreads();
        for (int i = tid; i < 1024; i += 256) {
            int row = i >> 5;
            int c4  = (i & 31) << 2;
            *reinterpret_cast<float4*>(&qs[row][c4]) =
                *reinterpret_cast<const float4*>(qb + row * Dd + c + c4);
            *reinterpret_cast<float4*>(&ks[row][c4]) =
                *reinterpret_cast<const float4*>(kb + row * Dd + c + c4);
        }
        __syncthreads();
#pragma unroll 2
        for (int dd = 0; dd < 128; dd += 4) {
            float4 q0 = *reinterpret_cast<const float4*>(&qs[tl][dd]);
            float4 q1 = *reinterpret_cast<const float4*>(&qs[tl + 16][dd]);
            float4 k0 = *reinterpret_cast<const float4*>(&ks[ts][dd]);
            float4 k1 = *reinterpret_cast<const float4*>(&ks[ts + 16][dd]);
            a00 = fmaf(q0.x, k0.x, a00); a00 = fmaf(q0.y, k0.y, a00);
            a00 = fmaf(q0.z, k0.z, a00); a00 = fmaf(q0.w, k0.w, a00);
            a01 = fmaf(q0.x, k1.x, a01); a01 = fmaf(q0.y, k1.y, a01);
            a01 = fmaf(q0.z, k1.z, a01); a01 = fmaf(q0.w, k1.w, a01);
            a10 = fmaf(q1.x, k0.x, a10); a10 = fmaf(q1.y, k0.y, a10);
            a10 = fmaf(q1.z, k0.z, a10); a10 = fmaf(q1.w, k0.w, a10);
            a11 = fmaf(q1.x, k1.x, a11); a11 = fmaf(q1.y, k1.y, a11);
            a11 = fmaf(q1.z, k1.z, a11); a11 = fmaf(q1.w, k1.w, a11);
        }
    }
    const float sc = 0.04419417382415922f;          // 1/sqrt(512)
    float* dst = sim01 + kc * (Bb * Lq * Sk);
    int l0 = lt * 32 + tl, s0 = st * 32 + ts;
    dst[(b * Lq + l0)      * Sk + s0]      = a00 * sc;
    dst[(b * Lq + l0)      * Sk + s0 + 16] = a01 * sc;
    dst[(b * Lq + l0 + 16) * Sk + s0]      = a10 * sc;
    dst[(b * Lq + l0 + 16) * Sk + s0 + 16] = a11 * sc;
}

// ---------------------------------------------------------------------------
// packed-pair gelu accumulate: y2 = 2*gelu(x); sums fold the 0.5 later.
__device__ __forceinline__ void gelu2(float2 hqv, float2 hkv, float2 gwv,
                                      float2& s1, float2& s2, float2& sw)
{
    const float P2   = 0.23164189f;            // 0.3275911/sqrt(2)
    const float A1f = 0.254829592f, A2f = -0.284496736f, A3f = 1.421413741f,
                A4f = -1.453152027f, A5f = 1.061405429f;
    const float NL2EH = -0.72134752044448170f; // -log2(e)/2

    float xa = hqv.x + hkv.x,        xb = hqv.y + hkv.y;
    float axa = fabsf(xa),           axb = fabsf(xb);
    float dda = fmaf(P2, axa, 1.0f), ddb = fmaf(P2, axb, 1.0f);
    float ta = __builtin_amdgcn_rcpf(dda), tb = __builtin_amdgcn_rcpf(ddb);
    float x2a = xa * xa,             x2b = xb * xb;
    float exa = __builtin_amdgcn_exp2f(x2a * NL2EH);
    float exb = __builtin_amdgcn_exp2f(x2b * NL2EH);
    float sa = fmaf(A5f, ta, A4f),   sb = fmaf(A5f, tb, A4f);
    sa = fmaf(sa, ta, A3f);          sb = fmaf(sb, tb, A3f);
    sa = fmaf(sa, ta, A2f);          sb = fmaf(sb, tb, A2f);
    sa = fmaf(sa, ta, A1f);          sb = fmaf(sb, tb, A1f);
    sa = sa * ta;                    sb = sb * tb;
    float Ea = fmaf(-sa, exa, 1.0f), Eb = fmaf(-sb, exb, 1.0f);
    float ya = fmaf(axa, Ea, xa),    yb = fmaf(axb, Eb, xb);   // = 2*gelu
    s1.x += ya;                      s1.y += yb;
    s2.x = fmaf(ya, ya, s2.x);       s2.y = fmaf(yb, yb, s2.y);
    sw.x = fmaf(ya, gwv.x, sw.x);    sw.y = fmaf(yb, gwv.y, sw.y);
}

// ---------------------------------------------------------------------------
// main: per (b,l,s) one pass over H -> threshold -> gumbel decision;
// flag |t|<1e-3 for f64 cleanup.
__global__ __launch_bounds__(256) void main_kernel(
    const float* __restrict__ hq, const float* __restrict__ hk,
    const float* __restrict__ sim0, const float* __restrict__ sim1,
    const float* __restrict__ gw_in, const float* __restrict__ scal,
    const float* __restrict__ gu, float* __restrict__ out,
    int* __restrict__ cnt, int* __restrict__ list)
{
    __shared__ __align__(16) float hq_t[16][260];
    __shared__ __align__(16) float hk_t[16][260];
    __shared__ __align__(16) float gw_s[256];
    int tid = threadIdx.x;
    int bx = blockIdx.x;
    int b  = bx / (24 * 24);
    int r  = bx % (24 * 24);
    int lt = r / 24, st = r % 24;

    const float* hqb = hq + (b * Lq + lt * 16) * Hh;
    const float* hkb = hk + (b * Sk + st * 16) * Hh;
#pragma unroll
    for (int i = 0; i < 4; ++i) {
        int idx4 = i * 256 + tid;            // 0..1023
        int row  = idx4 >> 6;
        int col4 = (idx4 & 63) << 2;
        *reinterpret_cast<float4*>(&hq_t[row][col4]) =
            *reinterpret_cast<const float4*>(hqb + row * Hh + col4);
        *reinterpret_cast<float4*>(&hk_t[row][col4]) =
            *reinterpret_cast<const float4*>(hkb + row * Hh + col4);
    }
    gw_s[tid] = gw_in[tid];
    __syncthreads();
    float gwsum  = scal[0];
    float bconst = scal[1];

    int tl = tid >> 4, ts = tid & 15;
    float2 s1 = make_float2(0.f, 0.f);
    float2 s2 = make_float2(0.f, 0.f);
    float2 sw = make_float2(0.f, 0.f);
#pragma unroll 2
    for (int h4 = 0; h4 < Hh; h4 += 4) {
        float4 hq4 = *reinterpret_cast<const float4*>(&hq_t[tl][h4]);
        float4 hk4 = *reinterpret_cast<const float4*>(&hk_t[ts][h4]);
        float4 gw4 = *reinterpret_cast<const float4*>(&gw_s[h4]);
        gelu2(make_float2(hq4.x, hq4.y), make_float2(hk4.x, hk4.y),
              make_float2(gw4.x, gw4.y), s1, s2, sw);
        gelu2(make_float2(hq4.z, hq4.w), make_float2(hk4.z, hk4.w),
              make_float2(gw4.z, gw4.w), s1, s2, sw);
    }
    float S1 = s1.x + s1.y;                   // = sum 2*gelu
    float S2 = s2.x + s2.y;                   // = sum 4*gelu^2
    float SW = 0.5f * (sw.x + sw.y);
    float mu   = S1 * (1.0f / 512.0f);
    float var  = S2 * (1.0f / 1024.0f) - mu * mu;
    float rstd = rsqrtf(var + 1e-5f);
    float thr  = rstd * (SW - mu * gwsum) + bconst;

    int l = lt * 16 + tl, s = st * 16 + ts;
    int idx = (b * Lq + l) * Sk + s;
    float  sv = sim0[idx] + sim1[idx];
    float2 uv = reinterpret_cast<const float2*>(gu)[idx];
    float u0 = fminf(fmaxf(uv.x, 1e-6f), 1.0f - 1e-6f);
    float u1 = fminf(fmaxf(uv.y, 1e-6f), 1.0f - 1e-6f);
    float g0 = -logf(-logf(u0));
    float g1 = -logf(-logf(u1));
    float t  = 0.2f * (sv - thr) + (g1 - g0);
    out[idx] = t > 0.0f ? 1.0f : 0.0f;
    if (fabsf(t) < 1e-3f) {
        int p = atomicAdd(cnt, 1);
        if (p < LIST_CAP) list[p] = idx;
    }
}

// ---------------------------------------------------------------------------
// cleanup: per flagged item, f64 finish using precomputed f64 projections.
__global__ __launch_bounds__(256) void cleanup_kernel(
    const float* __restrict__ q, const float* __restrict__ k,
    const double* __restrict__ hq_d, const double* __restrict__ hk_d,
    const float* __restrict__ b1,
    const float* __restrict__ gam, const float* __restrict__ bet,
    const float* __restrict__ W2, const float* __restrict__ b2,
    const float* __restrict__ gu, float* __restrict__ out,
    const int* __restrict__ cnt, const int* __restrict__ list)
{
    __shared__ double s0[256], s1[256], s2[256], s3[256];
    int tid = threadIdx.x;
    int n = *cnt;
    if (n > LIST_CAP) n = LIST_CAP;
    if (n == 0) return;

    double gw  = (double)gam[tid] * (double)W2[tid];
    double b1d = (double)b1[tid];
    s0[tid] = (double)bet[tid] * (double)W2[tid];
    s1[tid] = gw;
    __syncthreads();
    for (int o = 128; o > 0; o >>= 1) {
        if (tid < o) { s0[tid] += s0[tid + o]; s1[tid] += s1[tid + o]; }
        __syncthreads();
    }
    double bconst = s0[0] + (double)b2[0];
    double gwsum  = s1[0];
    __syncthreads();

    for (int it = blockIdx.x; it < n; it += gridDim.x) {
        int idx = list[it];
        int b   = idx / (Lq * Sk);
        int rem = idx % (Lq * Sk);
        int l = rem / Sk, s = rem % Sk;
        double x = (hq_d[(b * Lq + l) * Hh + tid]
                  + hk_d[(b * Sk + s) * Hh + tid]) + b1d;
        double y = 0.5 * x * (1.0 + erf(x * 0.70710678118654752440));
        const float* qrow = q + (b * Lq + l) * Dd;
        const float* krow = k + (b * Sk + s) * Dd;
        double sp = (double)qrow[tid] * (double)krow[tid]
                  + (double)qrow[tid + 256] * (double)krow[tid + 256];
        s0[tid] = y; s1[tid] = y * y; s2[tid] = y * gw; s3[tid] = sp;
        __syncthreads();
        for (int o = 128; o > 0; o >>= 1) {
            if (tid < o) {
                s0[tid] += s0[tid + o]; s1[tid] += s1[tid + o];
                s2[tid] += s2[tid + o]; s3[tid] += s3[tid + o];
            }
            __syncthreads();
        }
        if (tid == 0) {
            double mu   = s0[0] * (1.0 / 256.0);
            double var  = s1[0] * (1.0 / 256.0) - mu * mu;
            double rstd = 1.0 / sqrt(var + 1e-5);
            double thr  = rstd * (s2[0] - mu * gwsum) + bconst;
            double simv = s3[0] / 22.627416997969522;   // sqrt(512)
            float2 uv = reinterpret_cast<const float2*>(gu)[idx];
            double u0 = fmin(fmax((double)uv.x, 1e-6), 1.0 - 1e-6);
            double u1 = fmin(fmax((double)uv.y, 1e-6), 1.0 - 1e-6);
            double g0 = -log(-log(u0));
            double g1 = -log(-log(u1));
            double t  = 0.2 * (simv - thr) + (g1 - g0);
            out[idx] = t > 0.0 ? 1.0f : 0.0f;
        }
        __syncthreads();
    }
}

// ---------------------------------------------------------------------------
extern "C" void kernel_launch(void* const* d_in, const int* in_sizes, int n_in,
                              void* d_out, int out_size, void* d_ws, size_t ws_size,
                              hipStream_t stream)
{
    const float* q   = (const float*)d_in[0];
    const float* k   = (const float*)d_in[1];
    const float* qg  = (const float*)d_in[2];
    const float* kg  = (const float*)d_in[3];
    const float* W1  = (const float*)d_in[4];
    const float* b1  = (const float*)d_in[5];
    const float* gam = (const float*)d_in[6];
    const float* bet = (const float*)d_in[7];
    const float* W2  = (const float*)d_in[8];
    const float* b2  = (const float*)d_in[9];
    const float* gu  = (const float*)d_in[10];
    float* out = (float*)d_out;

    char*   ws   = (char*)d_ws;
    double* hq_d = (double*)(ws + HQD_OFF);
    double* hk_d = (double*)(ws + HKD_OFF);
    double* gq_d = (double*)(ws + GQD_OFF);
    double* gk_d = (double*)(ws + GKD_OFF);
    float*  hq   = (float*)(ws + HQ_OFF);
    float*  hk   = (float*)(ws + HK_OFF);
    float*  sim0 = (float*)(ws + SIM0_OFF);
    float*  sim1 = (float*)(ws + SIM1_OFF);
    float*  scal = (float*)(ws + SCAL_OFF);
    float*  gw   = (float*)(ws + GW_OFF);
    int*    cnt  = (int*)(ws + CNT_OFF);
    int*    list = (int*)(ws + LIST_OFF);

    hipMemsetAsync(cnt, 0, sizeof(int), stream);
    smalls_kernel<<<17, 256, 0, stream>>>(
        qg, kg, W1, gam, bet, W2, b2, gq_d, gk_d, gw, scal);
    projd_kernel<<<192, 512, 0, stream>>>(
        q, k, W1, b1, gq_d, gk_d, hq_d, hk_d, hq, hk);
    sim_kernel<<<2 * Bb * 144, 256, 0, stream>>>(q, k, sim0);
    main_kernel<<<Bb * 24 * 24, 256, 0, stream>>>(
        hq, hk, sim0, sim1, gw, scal, gu, out, cnt, list);
    cleanup_kernel<<<768, 256, 0, stream>>>(
        q, k, hq_d, hk_d, b1, gam, bet, W2, b2, gu, out, cnt, list);
}